// Round 2
// baseline (719.897 us; speedup 1.0000x reference)
//
#include <hip/hip_runtime.h>

#define B_ 4
#define SQ_ 2048
#define SKV_ 2048
#define E_ 1024
#define H_ 16
#define D_ 64

typedef __bf16 bf16x8 __attribute__((ext_vector_type(8)));
typedef __bf16 bf16x4 __attribute__((ext_vector_type(4)));
typedef float f32x4 __attribute__((ext_vector_type(4)));

__device__ inline f32x4 zero4() { f32x4 z = {0.f, 0.f, 0.f, 0.f}; return z; }

// Convert 8 consecutive f32 (32B-aligned) to a bf16x8 MFMA fragment.
__device__ inline bf16x8 cvt8(const float* __restrict__ p) {
    const float4 a = ((const float4*)p)[0];
    const float4 b = ((const float4*)p)[1];
    bf16x8 r;
    r[0] = (__bf16)a.x; r[1] = (__bf16)a.y; r[2] = (__bf16)a.z; r[3] = (__bf16)a.w;
    r[4] = (__bf16)b.x; r[5] = (__bf16)b.y; r[6] = (__bf16)b.z; r[7] = (__bf16)b.w;
    return r;
}

#define MFMA16(a, b, c) __builtin_amdgcn_mfma_f32_16x16x32_bf16(a, b, c, 0, 0, 0)

// exp(score/8) = 2^(score * 0.125 * log2(e)); the 0.18033688 factor is folded
// into qh at projection time so attention needs only v_exp_f32 per element.
#define QSCALE 0.18033688011112042f

// ---------------------------------------------------------------------------
// wo f32 [E][E] -> bf16 same layout (row n, col k — already B-operand friendly)
__global__ __launch_bounds__(256) void cast_wo_kernel(const float* __restrict__ wo,
                                                      __bf16* __restrict__ wo_bf) {
    int i = (blockIdx.x * 256 + threadIdx.x) * 4;
    float4 v = *(const float4*)(wo + i);
    wo_bf[i + 0] = (__bf16)v.x;
    wo_bf[i + 1] = (__bf16)v.y;
    wo_bf[i + 2] = (__bf16)v.z;
    wo_bf[i + 3] = (__bf16)v.w;
}

// ---------------------------------------------------------------------------
// Q projection: qh[b,h,s,e] = ((sum_d q[b,s,h*64+d] * wq[h,e,d]) + bq[h,e]) * QSCALE
__global__ __launch_bounds__(256) void proj_q_kernel(const float* __restrict__ q,
                                                     const float* __restrict__ wq,
                                                     const float* __restrict__ bq,
                                                     __bf16* __restrict__ qh) {
    const int w = threadIdx.x >> 6, lane = threadIdx.x & 63;
    const int l15 = lane & 15, quad = lane >> 4;
    const int b = blockIdx.z, h = blockIdx.y;
    const int s_base = blockIdx.x * 64 + w * 16;

    const float* qrow = q + ((size_t)b * SQ_ + s_base + l15) * E_ + h * D_ + quad * 8;
    bf16x8 a0 = cvt8(qrow);
    bf16x8 a1 = cvt8(qrow + 32);

    f32x4 acc[4] = {zero4(), zero4(), zero4(), zero4()};
#pragma unroll
    for (int nb = 0; nb < 4; ++nb) {
        const float* wrow = wq + (size_t)h * D_ * D_ + (nb * 16 + l15) * D_ + quad * 8;
        bf16x8 b0 = cvt8(wrow);
        bf16x8 b1 = cvt8(wrow + 32);
        acc[nb] = MFMA16(a0, b0, acc[nb]);
        acc[nb] = MFMA16(a1, b1, acc[nb]);
    }

    __bf16* obase = qh + ((size_t)(b * H_ + h) * SQ_ + s_base) * D_;
#pragma unroll
    for (int nb = 0; nb < 4; ++nb) {
        const int col = nb * 16 + l15;
        const float bias = bq[h * D_ + col];
#pragma unroll
        for (int r = 0; r < 4; ++r) {
            obase[(quad * 4 + r) * D_ + col] = (__bf16)((acc[nb][r] + bias) * QSCALE);
        }
    }
}

// ---------------------------------------------------------------------------
// KV projection: kh row-major [B,H,SKV,D]; vh stored TRANSPOSED and PERMUTED:
// within each 64-wide t-tile, actual col c = cb*16+l15 is stored at
// pos = (c&15)*4 + (c>>4), matching attention's P-store permutation so the
// PV contraction indexes agree. vh_p[b,h,d, t0 + pos].
__global__ __launch_bounds__(256) void proj_kv_kernel(const float* __restrict__ kv,
                                                      const float* __restrict__ wk,
                                                      const float* __restrict__ bk,
                                                      const float* __restrict__ wv,
                                                      const float* __restrict__ bv,
                                                      __bf16* __restrict__ kh,
                                                      __bf16* __restrict__ vh_p) {
    const int w = threadIdx.x >> 6, lane = threadIdx.x & 63;
    const int l15 = lane & 15, quad = lane >> 4;
    const int b = blockIdx.z, h = blockIdx.y;
    const int t_base = blockIdx.x * 64 + w * 16;

    const float* xrow = kv + ((size_t)b * SKV_ + t_base + l15) * E_ + h * D_ + quad * 8;
    bf16x8 a0 = cvt8(xrow);
    bf16x8 a1 = cvt8(xrow + 32);

    f32x4 acck[4] = {zero4(), zero4(), zero4(), zero4()};
    f32x4 accv[4] = {zero4(), zero4(), zero4(), zero4()};
#pragma unroll
    for (int nb = 0; nb < 4; ++nb) {
        const float* wkrow = wk + (size_t)h * D_ * D_ + (nb * 16 + l15) * D_ + quad * 8;
        const float* wvrow = wv + (size_t)h * D_ * D_ + (nb * 16 + l15) * D_ + quad * 8;
        bf16x8 bk0 = cvt8(wkrow);
        bf16x8 bk1 = cvt8(wkrow + 32);
        bf16x8 bv0 = cvt8(wvrow);
        bf16x8 bv1 = cvt8(wvrow + 32);
        acck[nb] = MFMA16(a0, bk0, acck[nb]);
        acck[nb] = MFMA16(a1, bk1, acck[nb]);
        accv[nb] = MFMA16(a0, bv0, accv[nb]);
        accv[nb] = MFMA16(a1, bv1, accv[nb]);
    }

    __bf16* kbase = kh + ((size_t)(b * H_ + h) * SKV_ + t_base) * D_;
    __bf16* vbase = vh_p + (size_t)(b * H_ + h) * D_ * SKV_;
#pragma unroll
    for (int nb = 0; nb < 4; ++nb) {
        const int col = nb * 16 + l15;
        const float biask = bk[h * D_ + col];
        const float biasv = bv[h * D_ + col];
#pragma unroll
        for (int r = 0; r < 4; ++r) {
            const int row = quad * 4 + r;  // t within this wave's 16-row slab
            kbase[row * D_ + col] = (__bf16)(acck[nb][r] + biask);
            // t = blk*64 + w*16 + row; tt = w*16+row; pos = (tt&15)*4 + (tt>>4) = row*4 + w
            vbase[(size_t)col * SKV_ + blockIdx.x * 64 + row * 4 + w] =
                (__bf16)(accv[nb][r] + biasv);
        }
    }
}

// ---------------------------------------------------------------------------
// Attention, no-max-subtraction exponential (scores are ~unit variance by
// construction; exp2 args bounded ~<15, sums < 1e8 — f32-safe).
// Block: 64 q-rows (4 waves x 16), kv-tile 64. Zero cross-lane shuffles:
// row sums via MFMA ones-column; P round-trips LDS in a permuted layout so
// writes are 8B-contiguous per lane.
// Grid: 1-D 2048, f = t*64 + g  (g = b*16+h) -> all tiles of one (b,h) share
// an XCD (xcd = f%8 = g%8) for K/V L2 locality.
__global__ __launch_bounds__(256) void attn_kernel(const __bf16* __restrict__ qh,
                                                   const __bf16* __restrict__ kh,
                                                   const __bf16* __restrict__ vh_p,
                                                   __bf16* __restrict__ ctx) {
    // row stride 72 bf16 = 144B: 16B-aligned, bank-phase-clean for b64/b128.
    __shared__ __bf16 p_lds[4][16][72];

    const int w = threadIdx.x >> 6, lane = threadIdx.x & 63;
    const int l15 = lane & 15, quad = lane >> 4;
    const int f = blockIdx.x;
    const int g = f & 63, t = f >> 6;
    const int b = g >> 4, h = g & 15;
    const int bh = b * H_ + h;
    const int s_base = t * 64 + w * 16;

    const __bf16* qbase = qh + ((size_t)bh * SQ_ + s_base + l15) * D_ + quad * 8;
    bf16x8 aq0 = *(const bf16x8*)qbase;
    bf16x8 aq1 = *(const bf16x8*)(qbase + 32);

    bf16x8 ones;
#pragma unroll
    for (int i = 0; i < 8; ++i) ones[i] = (__bf16)1.0f;

    f32x4 o[4] = {zero4(), zero4(), zero4(), zero4()};
    f32x4 ol = zero4();  // row sums (replicated over cols)

    const __bf16* kbase = kh + (size_t)bh * SKV_ * D_;
    const __bf16* vbase = vh_p + (size_t)bh * D_ * SKV_;

    for (int t0 = 0; t0 < SKV_; t0 += 64) {
        // S = (Q*QSCALE) K^T for this 16x64 tile (per wave), exp2-ready
        f32x4 s[4] = {zero4(), zero4(), zero4(), zero4()};
#pragma unroll
        for (int nb = 0; nb < 4; ++nb) {
            const __bf16* kr = kbase + (size_t)(t0 + nb * 16 + l15) * D_ + quad * 8;
            bf16x8 bk0 = *(const bf16x8*)kr;
            bf16x8 bk1 = *(const bf16x8*)(kr + 32);
            s[nb] = MFMA16(aq0, bk0, s[nb]);
            s[nb] = MFMA16(aq1, bk1, s[nb]);
        }
        // P = 2^S, packed store: lane's 4 values (cols cb*16+l15) land at
        // contiguous pos = l15*4 + cb  -> one 8B write per row.
#pragma unroll
        for (int r = 0; r < 4; ++r) {
            bf16x4 p;
            p[0] = (__bf16)__builtin_amdgcn_exp2f(s[0][r]);
            p[1] = (__bf16)__builtin_amdgcn_exp2f(s[1][r]);
            p[2] = (__bf16)__builtin_amdgcn_exp2f(s[2][r]);
            p[3] = (__bf16)__builtin_amdgcn_exp2f(s[3][r]);
            *(bf16x4*)&p_lds[w][quad * 4 + r][l15 * 4] = p;
        }
        // O += P V ; row sums += P * 1 (ones-column on the idle MFMA pipe)
#pragma unroll
        for (int ks = 0; ks < 2; ++ks) {
            bf16x8 ap = *(const bf16x8*)&p_lds[w][l15][ks * 32 + quad * 8];
#pragma unroll
            for (int nb = 0; nb < 4; ++nb) {
                const __bf16* vr = vbase + (size_t)(nb * 16 + l15) * SKV_ + t0 + ks * 32 + quad * 8;
                bf16x8 bv = *(const bf16x8*)vr;
                o[nb] = MFMA16(ap, bv, o[nb]);
            }
            ol = MFMA16(ap, ones, ol);
        }
    }

    __bf16* cbase = ctx + ((size_t)b * SQ_ + s_base) * E_ + h * D_;
#pragma unroll
    for (int r = 0; r < 4; ++r) {
        const float inv = 1.f / ol[r];
        const int row = quad * 4 + r;
#pragma unroll
        for (int nb = 0; nb < 4; ++nb) {
            cbase[row * E_ + nb * 16 + l15] = (__bf16)(o[nb][r] * inv);
        }
    }
}

// ---------------------------------------------------------------------------
// Output GEMM: out[m,n] = sum_k ctx[m,k] * wo[n,k] + bo[n]
// M=8192, N=1024, K=1024. Block tile 128x64 (4 waves x 32 rows).
__global__ __launch_bounds__(256) void ogemm_kernel(const __bf16* __restrict__ ctx,
                                                    const __bf16* __restrict__ wo_bf,
                                                    const float* __restrict__ bo,
                                                    float* __restrict__ out) {
    const int w = threadIdx.x >> 6, lane = threadIdx.x & 63;
    const int l15 = lane & 15, quad = lane >> 4;
    const int m_base = blockIdx.x * 128 + w * 32;
    const int n_base = blockIdx.y * 64;

    f32x4 acc[2][4] = {{zero4(), zero4(), zero4(), zero4()},
                       {zero4(), zero4(), zero4(), zero4()}};

    const __bf16* arow0 = ctx + (size_t)(m_base + l15) * E_ + quad * 8;
    const __bf16* arow1 = arow0 + (size_t)16 * E_;
    const __bf16* brow = wo_bf + (size_t)(n_base + l15) * E_ + quad * 8;

    for (int k0 = 0; k0 < E_; k0 += 32) {
        bf16x8 a0 = *(const bf16x8*)(arow0 + k0);
        bf16x8 a1 = *(const bf16x8*)(arow1 + k0);
#pragma unroll
        for (int nb = 0; nb < 4; ++nb) {
            bf16x8 bf = *(const bf16x8*)(brow + (size_t)nb * 16 * E_ + k0);
            acc[0][nb] = MFMA16(a0, bf, acc[0][nb]);
            acc[1][nb] = MFMA16(a1, bf, acc[1][nb]);
        }
    }

#pragma unroll
    for (int sub = 0; sub < 2; ++sub) {
#pragma unroll
        for (int nb = 0; nb < 4; ++nb) {
            const int col = n_base + nb * 16 + l15;
            const float bias = bo[col];
#pragma unroll
            for (int r = 0; r < 4; ++r) {
                const int row = m_base + sub * 16 + quad * 4 + r;
                out[(size_t)row * E_ + col] = acc[sub][nb][r] + bias;
            }
        }
    }
}

// ---------------------------------------------------------------------------
extern "C" void kernel_launch(void* const* d_in, const int* in_sizes, int n_in,
                              void* d_out, int out_size, void* d_ws, size_t ws_size,
                              hipStream_t stream) {
    const float* query = (const float*)d_in[0];
    const float* key_value = (const float*)d_in[1];
    const float* wq = (const float*)d_in[2];
    const float* bq = (const float*)d_in[3];
    const float* wk = (const float*)d_in[4];
    const float* bk = (const float*)d_in[5];
    const float* wv = (const float*)d_in[6];
    const float* bv = (const float*)d_in[7];
    const float* wo = (const float*)d_in[8];
    const float* bo = (const float*)d_in[9];
    float* out = (float*)d_out;

    // workspace layout (needs 66 MB): qh | kh | vh_p | ctx | wo_bf
    char* ws = (char*)d_ws;
    __bf16* qh = (__bf16*)(ws);                         // 16 MB [B,H,SQ,D]
    __bf16* kh = (__bf16*)(ws + (16u << 20));           // 16 MB [B,H,SKV,D]
    __bf16* vh_p = (__bf16*)(ws + (32u << 20));         // 16 MB [B,H,D,SKV] (permuted)
    __bf16* ctxb = (__bf16*)(ws + (48u << 20));         // 16 MB [B,SQ,E]
    __bf16* wo_bf = (__bf16*)(ws + (64u << 20));        // 2 MB  [E,E]

    hipLaunchKernelGGL(cast_wo_kernel, dim3(E_ * E_ / 1024), dim3(256), 0, stream, wo, wo_bf);
    hipLaunchKernelGGL(proj_q_kernel, dim3(SQ_ / 64, H_, B_), dim3(256), 0, stream,
                       query, wq, bq, qh);
    hipLaunchKernelGGL(proj_kv_kernel, dim3(SKV_ / 64, H_, B_), dim3(256), 0, stream,
                       key_value, wk, bk, wv, bv, kh, vh_p);
    hipLaunchKernelGGL(attn_kernel, dim3(B_ * H_ * (SQ_ / 64)), dim3(256), 0, stream,
                       qh, kh, vh_p, ctxb);
    hipLaunchKernelGGL(ogemm_kernel, dim3(B_ * SQ_ / 128, E_ / 64), dim3(256), 0, stream,
                       ctxb, wo_bf, bo, out);
}

// Round 4
// 504.713 us; speedup vs baseline: 1.4263x; 1.4263x over previous
//
#include <hip/hip_runtime.h>

#define B_ 4
#define SQ_ 2048
#define SKV_ 2048
#define E_ 1024
#define H_ 16
#define D_ 64

typedef __bf16 bf16x8 __attribute__((ext_vector_type(8)));
typedef __bf16 bf16x4 __attribute__((ext_vector_type(4)));
typedef float f32x4 __attribute__((ext_vector_type(4)));

__device__ inline f32x4 zero4() { f32x4 z = {0.f, 0.f, 0.f, 0.f}; return z; }

// Convert 8 consecutive f32 (32B-aligned) to a bf16x8 MFMA fragment.
__device__ inline bf16x8 cvt8(const float* __restrict__ p) {
    const float4 a = ((const float4*)p)[0];
    const float4 b = ((const float4*)p)[1];
    bf16x8 r;
    r[0] = (__bf16)a.x; r[1] = (__bf16)a.y; r[2] = (__bf16)a.z; r[3] = (__bf16)a.w;
    r[4] = (__bf16)b.x; r[5] = (__bf16)b.y; r[6] = (__bf16)b.z; r[7] = (__bf16)b.w;
    return r;
}

#define MFMA16(a, b, c) __builtin_amdgcn_mfma_f32_16x16x32_bf16(a, b, c, 0, 0, 0)

// exp(score/8) = 2^(score * 0.125 * log2(e)); folded into qh at projection.
#define QSCALE 0.18033688011112042f

// ---------------------------------------------------------------------------
__global__ __launch_bounds__(256) void cast_wo_kernel(const float* __restrict__ wo,
                                                      __bf16* __restrict__ wo_bf) {
    int i = (blockIdx.x * 256 + threadIdx.x) * 4;
    float4 v = *(const float4*)(wo + i);
    wo_bf[i + 0] = (__bf16)v.x;
    wo_bf[i + 1] = (__bf16)v.y;
    wo_bf[i + 2] = (__bf16)v.z;
    wo_bf[i + 3] = (__bf16)v.w;
}

// ---------------------------------------------------------------------------
// Q projection (scaled by QSCALE for exp2-based softmax).
__global__ __launch_bounds__(256) void proj_q_kernel(const float* __restrict__ q,
                                                     const float* __restrict__ wq,
                                                     const float* __restrict__ bq,
                                                     __bf16* __restrict__ qh) {
    const int w = threadIdx.x >> 6, lane = threadIdx.x & 63;
    const int l15 = lane & 15, quad = lane >> 4;
    const int b = blockIdx.z, h = blockIdx.y;
    const int s_base = blockIdx.x * 64 + w * 16;

    const float* qrow = q + ((size_t)b * SQ_ + s_base + l15) * E_ + h * D_ + quad * 8;
    bf16x8 a0 = cvt8(qrow);
    bf16x8 a1 = cvt8(qrow + 32);

    f32x4 acc[4] = {zero4(), zero4(), zero4(), zero4()};
#pragma unroll
    for (int nb = 0; nb < 4; ++nb) {
        const float* wrow = wq + (size_t)h * D_ * D_ + (nb * 16 + l15) * D_ + quad * 8;
        bf16x8 b0 = cvt8(wrow);
        bf16x8 b1 = cvt8(wrow + 32);
        acc[nb] = MFMA16(a0, b0, acc[nb]);
        acc[nb] = MFMA16(a1, b1, acc[nb]);
    }

    __bf16* obase = qh + ((size_t)(b * H_ + h) * SQ_ + s_base) * D_;
#pragma unroll
    for (int nb = 0; nb < 4; ++nb) {
        const int col = nb * 16 + l15;
        const float bias = bq[h * D_ + col];
#pragma unroll
        for (int r = 0; r < 4; ++r) {
            obase[(quad * 4 + r) * D_ + col] = (__bf16)((acc[nb][r] + bias) * QSCALE);
        }
    }
}

// ---------------------------------------------------------------------------
// KV projection: kh row-major [B,H,SKV,D]; vh transposed+permuted:
// col c of a 64-tile stored at pos (c&15)*4 + (c>>4) to match P's LDS layout.
__global__ __launch_bounds__(256) void proj_kv_kernel(const float* __restrict__ kv,
                                                      const float* __restrict__ wk,
                                                      const float* __restrict__ bk,
                                                      const float* __restrict__ wv,
                                                      const float* __restrict__ bv,
                                                      __bf16* __restrict__ kh,
                                                      __bf16* __restrict__ vh_p) {
    const int w = threadIdx.x >> 6, lane = threadIdx.x & 63;
    const int l15 = lane & 15, quad = lane >> 4;
    const int b = blockIdx.z, h = blockIdx.y;
    const int t_base = blockIdx.x * 64 + w * 16;

    const float* xrow = kv + ((size_t)b * SKV_ + t_base + l15) * E_ + h * D_ + quad * 8;
    bf16x8 a0 = cvt8(xrow);
    bf16x8 a1 = cvt8(xrow + 32);

    f32x4 acck[4] = {zero4(), zero4(), zero4(), zero4()};
    f32x4 accv[4] = {zero4(), zero4(), zero4(), zero4()};
#pragma unroll
    for (int nb = 0; nb < 4; ++nb) {
        const float* wkrow = wk + (size_t)h * D_ * D_ + (nb * 16 + l15) * D_ + quad * 8;
        const float* wvrow = wv + (size_t)h * D_ * D_ + (nb * 16 + l15) * D_ + quad * 8;
        bf16x8 bk0 = cvt8(wkrow);
        bf16x8 bk1 = cvt8(wkrow + 32);
        bf16x8 bv0 = cvt8(wvrow);
        bf16x8 bv1 = cvt8(wvrow + 32);
        acck[nb] = MFMA16(a0, bk0, acck[nb]);
        acck[nb] = MFMA16(a1, bk1, acck[nb]);
        accv[nb] = MFMA16(a0, bv0, accv[nb]);
        accv[nb] = MFMA16(a1, bv1, accv[nb]);
    }

    __bf16* kbase = kh + ((size_t)(b * H_ + h) * SKV_ + t_base) * D_;
    __bf16* vbase = vh_p + (size_t)(b * H_ + h) * D_ * SKV_;
#pragma unroll
    for (int nb = 0; nb < 4; ++nb) {
        const int col = nb * 16 + l15;
        const float biask = bk[h * D_ + col];
        const float biasv = bv[h * D_ + col];
#pragma unroll
        for (int r = 0; r < 4; ++r) {
            const int row = quad * 4 + r;
            kbase[row * D_ + col] = (__bf16)(acck[nb][r] + biask);
            // tt = w*16+row within 64-tile; pos = (tt&15)*4 + (tt>>4) = row*4 + w
            vbase[(size_t)col * SKV_ + blockIdx.x * 64 + row * 4 + w] =
                (__bf16)(accv[nb][r] + biasv);
        }
    }
}

// ---------------------------------------------------------------------------
// Attention, software-pipelined. Each wave: 32 q-rows (two 16-row MFMA tiles)
// sharing one K/V fragment set. V(t) loads issue at iteration top (consumed
// ~400cyc later after QK+exp); K(t+1) prefetched right after QK(t) (consumed
// next iteration, covered by exp+LDS+PV). No cross-lane ops; row sums via
// MFMA ones-column; no max subtraction (scores unit-variance by construction).
// Grid 1-D 1024: f = t*64 + g, g=b*16+h -> all tiles of one (b,h) on one XCD.
__global__ __launch_bounds__(256) void attn_kernel(const __bf16* __restrict__ qh,
                                                   const __bf16* __restrict__ kh,
                                                   const __bf16* __restrict__ vh_p,
                                                   __bf16* __restrict__ ctx) {
    // Permuted P row spans 64 positions (pos = l15*4 + cb). Row stride 72
    // bf16 = 144B: >=64, 16B-aligned, bank-phase-clean for b64/b128.
    // (R3 bug: stride 40 < 64 made PV reads alias the next row.)
    __shared__ __bf16 p_lds[4][2][16][72];

    const int w = threadIdx.x >> 6, lane = threadIdx.x & 63;
    const int l15 = lane & 15, quad = lane >> 4;
    const int f = blockIdx.x;
    const int g = f & 63, t = f >> 6;
    const int b = g >> 4, h = g & 15;
    const int bh = b * H_ + h;
    const int s_base = t * 128 + w * 32;

    bf16x8 aq[2][2];
#pragma unroll
    for (int qt = 0; qt < 2; ++qt) {
        const __bf16* qb = qh + ((size_t)bh * SQ_ + s_base + qt * 16 + l15) * D_ + quad * 8;
        aq[qt][0] = *(const bf16x8*)qb;
        aq[qt][1] = *(const bf16x8*)(qb + 32);
    }

    bf16x8 ones;
#pragma unroll
    for (int i = 0; i < 8; ++i) ones[i] = (__bf16)1.0f;

    f32x4 o[2][4];
    f32x4 ol[2];
#pragma unroll
    for (int qt = 0; qt < 2; ++qt) {
        ol[qt] = zero4();
#pragma unroll
        for (int nb = 0; nb < 4; ++nb) o[qt][nb] = zero4();
    }

    const __bf16* kbase = kh + (size_t)bh * SKV_ * D_;
    const __bf16* vbase = vh_p + (size_t)bh * D_ * SKV_;

    // preload K fragments for tile 0
    bf16x8 kf[4][2];
#pragma unroll
    for (int nb = 0; nb < 4; ++nb) {
        const __bf16* kr = kbase + (size_t)(nb * 16 + l15) * D_ + quad * 8;
        kf[nb][0] = *(const bf16x8*)kr;
        kf[nb][1] = *(const bf16x8*)(kr + 32);
    }

    for (int it = 0; it < SKV_ / 64; ++it) {
        const int t0 = it * 64;
        // V loads for this tile — issued first so K prefetch (below) can stay
        // in flight while V is consumed (vmcnt ordering).
        bf16x8 vf[4][2];
#pragma unroll
        for (int nb = 0; nb < 4; ++nb) {
            const __bf16* vr = vbase + (size_t)(nb * 16 + l15) * SKV_ + t0 + quad * 8;
            vf[nb][0] = *(const bf16x8*)vr;
            vf[nb][1] = *(const bf16x8*)(vr + 32);
        }
        // QK^T for both q-tiles using current K regs
        f32x4 s[2][4];
#pragma unroll
        for (int qt = 0; qt < 2; ++qt)
#pragma unroll
            for (int nb = 0; nb < 4; ++nb) s[qt][nb] = zero4();
#pragma unroll
        for (int nb = 0; nb < 4; ++nb) {
#pragma unroll
            for (int qt = 0; qt < 2; ++qt) {
                s[qt][nb] = MFMA16(aq[qt][0], kf[nb][0], s[qt][nb]);
                s[qt][nb] = MFMA16(aq[qt][1], kf[nb][1], s[qt][nb]);
            }
        }
        // prefetch K for next tile (wrap on last iter; loads discarded)
        const int tn = (t0 + 64) & (SKV_ - 1);
#pragma unroll
        for (int nb = 0; nb < 4; ++nb) {
            const __bf16* kr = kbase + (size_t)(tn + nb * 16 + l15) * D_ + quad * 8;
            kf[nb][0] = *(const bf16x8*)kr;
            kf[nb][1] = *(const bf16x8*)(kr + 32);
        }
        // P = 2^S, packed 8B store per row into permuted LDS layout
#pragma unroll
        for (int qt = 0; qt < 2; ++qt) {
#pragma unroll
            for (int r = 0; r < 4; ++r) {
                bf16x4 p;
                p[0] = (__bf16)__builtin_amdgcn_exp2f(s[qt][0][r]);
                p[1] = (__bf16)__builtin_amdgcn_exp2f(s[qt][1][r]);
                p[2] = (__bf16)__builtin_amdgcn_exp2f(s[qt][2][r]);
                p[3] = (__bf16)__builtin_amdgcn_exp2f(s[qt][3][r]);
                *(bf16x4*)&p_lds[w][qt][quad * 4 + r][l15 * 4] = p;
            }
        }
        // O += P V ; row sums += P * ones
#pragma unroll
        for (int ks = 0; ks < 2; ++ks) {
#pragma unroll
            for (int qt = 0; qt < 2; ++qt) {
                bf16x8 ap = *(const bf16x8*)&p_lds[w][qt][l15][ks * 32 + quad * 8];
#pragma unroll
                for (int nb = 0; nb < 4; ++nb)
                    o[qt][nb] = MFMA16(ap, vf[nb][ks], o[qt][nb]);
                ol[qt] = MFMA16(ap, ones, ol[qt]);
            }
        }
    }

    __bf16* cbase = ctx + ((size_t)b * SQ_ + s_base) * E_ + h * D_;
#pragma unroll
    for (int qt = 0; qt < 2; ++qt) {
#pragma unroll
        for (int r = 0; r < 4; ++r) {
            const float inv = 1.f / ol[qt][r];
            const int row = qt * 16 + quad * 4 + r;
#pragma unroll
            for (int nb = 0; nb < 4; ++nb) {
                cbase[row * E_ + nb * 16 + l15] = (__bf16)(o[qt][nb][r] * inv);
            }
        }
    }
}

// ---------------------------------------------------------------------------
// Output GEMM: out[m,n] = sum_k ctx[m,k] * wo[n,k] + bo[n]
// M=8192, N=1024, K=1024. Block 128x64 (4 waves x 32 rows), double-buffered
// fragment prefetch. Grid 1-D 1024: f = nblk*64 + mblk -> all 16 n-blocks of
// one m-stripe share an XCD (A-tile stays in that XCD's L2).
__global__ __launch_bounds__(256) void ogemm_kernel(const __bf16* __restrict__ ctx,
                                                    const __bf16* __restrict__ wo_bf,
                                                    const float* __restrict__ bo,
                                                    float* __restrict__ out) {
    const int w = threadIdx.x >> 6, lane = threadIdx.x & 63;
    const int l15 = lane & 15, quad = lane >> 4;
    const int f = blockIdx.x;
    const int mblk = f & 63, nblk = f >> 6;
    const int m_base = mblk * 128 + w * 32;
    const int n_base = nblk * 64;

    f32x4 acc[2][4] = {{zero4(), zero4(), zero4(), zero4()},
                       {zero4(), zero4(), zero4(), zero4()}};

    const __bf16* arow0 = ctx + (size_t)(m_base + l15) * E_ + quad * 8;
    const __bf16* arow1 = arow0 + (size_t)16 * E_;
    const __bf16* brow = wo_bf + (size_t)(n_base + l15) * E_ + quad * 8;

    // preload k=0 fragment set
    bf16x8 a0 = *(const bf16x8*)(arow0);
    bf16x8 a1 = *(const bf16x8*)(arow1);
    bf16x8 bb[4];
#pragma unroll
    for (int nb = 0; nb < 4; ++nb) bb[nb] = *(const bf16x8*)(brow + (size_t)nb * 16 * E_);

    for (int kk = 0; kk < E_; kk += 64) {
        // prefetch k = kk+32
        bf16x8 a0n = *(const bf16x8*)(arow0 + kk + 32);
        bf16x8 a1n = *(const bf16x8*)(arow1 + kk + 32);
        bf16x8 bbn[4];
#pragma unroll
        for (int nb = 0; nb < 4; ++nb)
            bbn[nb] = *(const bf16x8*)(brow + (size_t)nb * 16 * E_ + kk + 32);
#pragma unroll
        for (int nb = 0; nb < 4; ++nb) {
            acc[0][nb] = MFMA16(a0, bb[nb], acc[0][nb]);
            acc[1][nb] = MFMA16(a1, bb[nb], acc[1][nb]);
        }
        // prefetch k = kk+64 (wrap on last; discarded)
        const int k2 = (kk + 64) & (E_ - 1);
        a0 = *(const bf16x8*)(arow0 + k2);
        a1 = *(const bf16x8*)(arow1 + k2);
#pragma unroll
        for (int nb = 0; nb < 4; ++nb)
            bb[nb] = *(const bf16x8*)(brow + (size_t)nb * 16 * E_ + k2);
#pragma unroll
        for (int nb = 0; nb < 4; ++nb) {
            acc[0][nb] = MFMA16(a0n, bbn[nb], acc[0][nb]);
            acc[1][nb] = MFMA16(a1n, bbn[nb], acc[1][nb]);
        }
    }

#pragma unroll
    for (int sub = 0; sub < 2; ++sub) {
#pragma unroll
        for (int nb = 0; nb < 4; ++nb) {
            const int col = n_base + nb * 16 + l15;
            const float bias = bo[col];
#pragma unroll
            for (int r = 0; r < 4; ++r) {
                const int row = m_base + sub * 16 + quad * 4 + r;
                out[(size_t)row * E_ + col] = acc[sub][nb][r] + bias;
            }
        }
    }
}

// ---------------------------------------------------------------------------
extern "C" void kernel_launch(void* const* d_in, const int* in_sizes, int n_in,
                              void* d_out, int out_size, void* d_ws, size_t ws_size,
                              hipStream_t stream) {
    const float* query = (const float*)d_in[0];
    const float* key_value = (const float*)d_in[1];
    const float* wq = (const float*)d_in[2];
    const float* bq = (const float*)d_in[3];
    const float* wk = (const float*)d_in[4];
    const float* bk = (const float*)d_in[5];
    const float* wv = (const float*)d_in[6];
    const float* bv = (const float*)d_in[7];
    const float* wo = (const float*)d_in[8];
    const float* bo = (const float*)d_in[9];
    float* out = (float*)d_out;

    // workspace layout (needs 66 MB): qh | kh | vh_p | ctx | wo_bf
    char* ws = (char*)d_ws;
    __bf16* qh = (__bf16*)(ws);                         // 16 MB [B,H,SQ,D]
    __bf16* kh = (__bf16*)(ws + (16u << 20));           // 16 MB [B,H,SKV,D]
    __bf16* vh_p = (__bf16*)(ws + (32u << 20));         // 16 MB [B,H,D,SKV] (permuted)
    __bf16* ctxb = (__bf16*)(ws + (48u << 20));         // 16 MB [B,SQ,E]
    __bf16* wo_bf = (__bf16*)(ws + (64u << 20));        // 2 MB  [E,E]

    hipLaunchKernelGGL(cast_wo_kernel, dim3(E_ * E_ / 1024), dim3(256), 0, stream, wo, wo_bf);
    hipLaunchKernelGGL(proj_q_kernel, dim3(SQ_ / 64, H_, B_), dim3(256), 0, stream,
                       query, wq, bq, qh);
    hipLaunchKernelGGL(proj_kv_kernel, dim3(SKV_ / 64, H_, B_), dim3(256), 0, stream,
                       key_value, wk, bk, wv, bv, kh, vh_p);
    hipLaunchKernelGGL(attn_kernel, dim3(B_ * H_ * (SQ_ / 128)), dim3(256), 0, stream,
                       qh, kh, vh_p, ctxb);
    hipLaunchKernelGGL(ogemm_kernel, dim3((B_ * SQ_ / 128) * (E_ / 64)), dim3(256), 0, stream,
                       ctxb, wo_bf, bo, out);
}

// Round 5
// 456.294 us; speedup vs baseline: 1.5777x; 1.1061x over previous
//
#include <hip/hip_runtime.h>

#define B_ 4
#define SQ_ 2048
#define SKV_ 2048
#define E_ 1024
#define H_ 16
#define D_ 64

typedef __bf16 bf16x8 __attribute__((ext_vector_type(8)));
typedef __bf16 bf16x4 __attribute__((ext_vector_type(4)));
typedef float f32x4 __attribute__((ext_vector_type(4)));

__device__ inline f32x4 zero4() { f32x4 z = {0.f, 0.f, 0.f, 0.f}; return z; }

// Convert 8 consecutive f32 (32B-aligned) to a bf16x8 MFMA fragment.
__device__ inline bf16x8 cvt8(const float* __restrict__ p) {
    const float4 a = ((const float4*)p)[0];
    const float4 b = ((const float4*)p)[1];
    bf16x8 r;
    r[0] = (__bf16)a.x; r[1] = (__bf16)a.y; r[2] = (__bf16)a.z; r[3] = (__bf16)a.w;
    r[4] = (__bf16)b.x; r[5] = (__bf16)b.y; r[6] = (__bf16)b.z; r[7] = (__bf16)b.w;
    return r;
}

#define MFMA16(a, b, c) __builtin_amdgcn_mfma_f32_16x16x32_bf16(a, b, c, 0, 0, 0)

// exp(score/8) = 2^(score * 0.125 * log2(e)); folded into qh at projection.
#define QSCALE 0.18033688011112042f

// ---------------------------------------------------------------------------
__global__ __launch_bounds__(256) void cast_wo_kernel(const float* __restrict__ wo,
                                                      __bf16* __restrict__ wo_bf) {
    int i = (blockIdx.x * 256 + threadIdx.x) * 4;
    float4 v = *(const float4*)(wo + i);
    wo_bf[i + 0] = (__bf16)v.x;
    wo_bf[i + 1] = (__bf16)v.y;
    wo_bf[i + 2] = (__bf16)v.z;
    wo_bf[i + 3] = (__bf16)v.w;
}

// ---------------------------------------------------------------------------
// Q projection (scaled by QSCALE for exp2-based softmax).
__global__ __launch_bounds__(256) void proj_q_kernel(const float* __restrict__ q,
                                                     const float* __restrict__ wq,
                                                     const float* __restrict__ bq,
                                                     __bf16* __restrict__ qh) {
    const int w = threadIdx.x >> 6, lane = threadIdx.x & 63;
    const int l15 = lane & 15, quad = lane >> 4;
    const int b = blockIdx.z, h = blockIdx.y;
    const int s_base = blockIdx.x * 64 + w * 16;

    const float* qrow = q + ((size_t)b * SQ_ + s_base + l15) * E_ + h * D_ + quad * 8;
    bf16x8 a0 = cvt8(qrow);
    bf16x8 a1 = cvt8(qrow + 32);

    f32x4 acc[4] = {zero4(), zero4(), zero4(), zero4()};
#pragma unroll
    for (int nb = 0; nb < 4; ++nb) {
        const float* wrow = wq + (size_t)h * D_ * D_ + (nb * 16 + l15) * D_ + quad * 8;
        bf16x8 b0 = cvt8(wrow);
        bf16x8 b1 = cvt8(wrow + 32);
        acc[nb] = MFMA16(a0, b0, acc[nb]);
        acc[nb] = MFMA16(a1, b1, acc[nb]);
    }

    __bf16* obase = qh + ((size_t)(b * H_ + h) * SQ_ + s_base) * D_;
#pragma unroll
    for (int nb = 0; nb < 4; ++nb) {
        const int col = nb * 16 + l15;
        const float bias = bq[h * D_ + col];
#pragma unroll
        for (int r = 0; r < 4; ++r) {
            obase[(quad * 4 + r) * D_ + col] = (__bf16)((acc[nb][r] + bias) * QSCALE);
        }
    }
}

// ---------------------------------------------------------------------------
// KV projection: kh row-major [B,H,SKV,D]; vh transposed+permuted:
// col c of a 64-tile stored at pos (c&15)*4 + (c>>4) to match P's LDS layout.
__global__ __launch_bounds__(256) void proj_kv_kernel(const float* __restrict__ kv,
                                                      const float* __restrict__ wk,
                                                      const float* __restrict__ bk,
                                                      const float* __restrict__ wv,
                                                      const float* __restrict__ bv,
                                                      __bf16* __restrict__ kh,
                                                      __bf16* __restrict__ vh_p) {
    const int w = threadIdx.x >> 6, lane = threadIdx.x & 63;
    const int l15 = lane & 15, quad = lane >> 4;
    const int b = blockIdx.z, h = blockIdx.y;
    const int t_base = blockIdx.x * 64 + w * 16;

    const float* xrow = kv + ((size_t)b * SKV_ + t_base + l15) * E_ + h * D_ + quad * 8;
    bf16x8 a0 = cvt8(xrow);
    bf16x8 a1 = cvt8(xrow + 32);

    f32x4 acck[4] = {zero4(), zero4(), zero4(), zero4()};
    f32x4 accv[4] = {zero4(), zero4(), zero4(), zero4()};
#pragma unroll
    for (int nb = 0; nb < 4; ++nb) {
        const float* wkrow = wk + (size_t)h * D_ * D_ + (nb * 16 + l15) * D_ + quad * 8;
        const float* wvrow = wv + (size_t)h * D_ * D_ + (nb * 16 + l15) * D_ + quad * 8;
        bf16x8 bk0 = cvt8(wkrow);
        bf16x8 bk1 = cvt8(wkrow + 32);
        bf16x8 bv0 = cvt8(wvrow);
        bf16x8 bv1 = cvt8(wvrow + 32);
        acck[nb] = MFMA16(a0, bk0, acck[nb]);
        acck[nb] = MFMA16(a1, bk1, acck[nb]);
        accv[nb] = MFMA16(a0, bv0, accv[nb]);
        accv[nb] = MFMA16(a1, bv1, accv[nb]);
    }

    __bf16* kbase = kh + ((size_t)(b * H_ + h) * SKV_ + t_base) * D_;
    __bf16* vbase = vh_p + (size_t)(b * H_ + h) * D_ * SKV_;
#pragma unroll
    for (int nb = 0; nb < 4; ++nb) {
        const int col = nb * 16 + l15;
        const float biask = bk[h * D_ + col];
        const float biasv = bv[h * D_ + col];
#pragma unroll
        for (int r = 0; r < 4; ++r) {
            const int row = quad * 4 + r;
            kbase[row * D_ + col] = (__bf16)(acck[nb][r] + biask);
            // tt = w*16+row within 64-tile; pos = (tt&15)*4 + (tt>>4) = row*4 + w
            vbase[(size_t)col * SKV_ + blockIdx.x * 64 + row * 4 + w] =
                (__bf16)(accv[nb][r] + biasv);
        }
    }
}

// ---------------------------------------------------------------------------
// Attention v3: 64 q-rows per wave (4 q-tiles), kv-tile 64. K/V loads
// amortized over 4 q-tiles (L2 traffic 2.1 GB -> 1.05 GB). QK+exp processed
// per-qt sequentially (caps live regs); K double-buffered across a x2-unrolled
// tile loop; V issued at tile top, consumed at tile end. Row sums as per-lane
// partials, reduced by 4 shuffles/row in the epilogue only. No barriers.
// Grid 1-D 512: f = t*64 + g, g=b*16+h -> all tiles of one (b,h) on one XCD.
__global__ __launch_bounds__(256, 2) void attn_kernel(const __bf16* __restrict__ qh,
                                                      const __bf16* __restrict__ kh,
                                                      const __bf16* __restrict__ vh_p,
                                                      __bf16* __restrict__ ctx) {
    // Permuted P row spans 64 positions (pos = l15*4 + cb). Row stride 72
    // bf16 = 144B: >=64, 16B-aligned, bank-phase-clean for b64/b128.
    __shared__ __bf16 p_lds[4][4][16][72];  // [wave][qt][row][col] = 36.9 KB

    const int w = threadIdx.x >> 6, lane = threadIdx.x & 63;
    const int l15 = lane & 15, quad = lane >> 4;
    const int f = blockIdx.x;
    const int g = f & 63, t = f >> 6;
    const int b = g >> 4, h = g & 15;
    const int bh = b * H_ + h;
    const int s_base = t * 256 + w * 64;

    bf16x8 aq[4][2];
#pragma unroll
    for (int qt = 0; qt < 4; ++qt) {
        const __bf16* qb = qh + ((size_t)bh * SQ_ + s_base + qt * 16 + l15) * D_ + quad * 8;
        aq[qt][0] = *(const bf16x8*)qb;
        aq[qt][1] = *(const bf16x8*)(qb + 32);
    }

    f32x4 o[4][4];
    float l_r[4][4];
#pragma unroll
    for (int qt = 0; qt < 4; ++qt) {
#pragma unroll
        for (int nb = 0; nb < 4; ++nb) o[qt][nb] = zero4();
#pragma unroll
        for (int r = 0; r < 4; ++r) l_r[qt][r] = 0.f;
    }

    const __bf16* kbase = kh + (size_t)bh * SKV_ * D_;
    const __bf16* vbase = vh_p + (size_t)bh * D_ * SKV_;

    bf16x8 kfA[4][2], kfB[4][2];
    // preload K fragments for tile 0 into kfA
#pragma unroll
    for (int nb = 0; nb < 4; ++nb) {
        const __bf16* kr = kbase + (size_t)(nb * 16 + l15) * D_ + quad * 8;
        kfA[nb][0] = *(const bf16x8*)kr;
        kfA[nb][1] = *(const bf16x8*)(kr + 32);
    }

    // one kv-tile: uses kcur, prefetches next tile's K into knext
    auto tile_body = [&](int t0, bf16x8 (&kcur)[4][2], bf16x8 (&knext)[4][2]) {
        // V loads for this tile — issued first, consumed at tile end.
        bf16x8 vf[4][2];
#pragma unroll
        for (int nb = 0; nb < 4; ++nb) {
            const __bf16* vr = vbase + (size_t)(nb * 16 + l15) * SKV_ + t0 + quad * 8;
            vf[nb][0] = *(const bf16x8*)vr;
            vf[nb][1] = *(const bf16x8*)(vr + 32);
        }
        // QK^T + exp per q-tile (keeps only one s-set live at a time)
#pragma unroll
        for (int qt = 0; qt < 4; ++qt) {
            f32x4 s[4] = {zero4(), zero4(), zero4(), zero4()};
#pragma unroll
            for (int nb = 0; nb < 4; ++nb) {
                s[nb] = MFMA16(aq[qt][0], kcur[nb][0], s[nb]);
                s[nb] = MFMA16(aq[qt][1], kcur[nb][1], s[nb]);
            }
#pragma unroll
            for (int r = 0; r < 4; ++r) {
                const float p0 = __builtin_amdgcn_exp2f(s[0][r]);
                const float p1 = __builtin_amdgcn_exp2f(s[1][r]);
                const float p2 = __builtin_amdgcn_exp2f(s[2][r]);
                const float p3 = __builtin_amdgcn_exp2f(s[3][r]);
                l_r[qt][r] += (p0 + p1) + (p2 + p3);
                bf16x4 p;
                p[0] = (__bf16)p0; p[1] = (__bf16)p1;
                p[2] = (__bf16)p2; p[3] = (__bf16)p3;
                *(bf16x4*)&p_lds[w][qt][quad * 4 + r][l15 * 4] = p;
            }
        }
        // prefetch K for next tile (wrap on last iter; loads discarded)
        const int tn = (t0 + 64) & (SKV_ - 1);
#pragma unroll
        for (int nb = 0; nb < 4; ++nb) {
            const __bf16* kr = kbase + (size_t)(tn + nb * 16 + l15) * D_ + quad * 8;
            knext[nb][0] = *(const bf16x8*)kr;
            knext[nb][1] = *(const bf16x8*)(kr + 32);
        }
        // O += P V
#pragma unroll
        for (int ks = 0; ks < 2; ++ks) {
#pragma unroll
            for (int qt = 0; qt < 4; ++qt) {
                bf16x8 ap = *(const bf16x8*)&p_lds[w][qt][l15][ks * 32 + quad * 8];
#pragma unroll
                for (int nb = 0; nb < 4; ++nb)
                    o[qt][nb] = MFMA16(ap, vf[nb][ks], o[qt][nb]);
            }
        }
    };

    for (int it = 0; it < SKV_ / 64; it += 2) {
        tile_body(it * 64, kfA, kfB);
        tile_body(it * 64 + 64, kfB, kfA);
    }

    __bf16* cbase = ctx + ((size_t)b * SQ_ + s_base) * E_ + h * D_;
#pragma unroll
    for (int qt = 0; qt < 4; ++qt) {
#pragma unroll
        for (int r = 0; r < 4; ++r) {
            // full row sum: reduce partials across the 16 lanes of this quad
            float l = l_r[qt][r];
            l += __shfl_xor(l, 1);
            l += __shfl_xor(l, 2);
            l += __shfl_xor(l, 4);
            l += __shfl_xor(l, 8);
            const float inv = 1.f / l;
            const int row = qt * 16 + quad * 4 + r;
#pragma unroll
            for (int nb = 0; nb < 4; ++nb) {
                cbase[row * E_ + nb * 16 + l15] = (__bf16)(o[qt][nb][r] * inv);
            }
        }
    }
}

// ---------------------------------------------------------------------------
// Output GEMM: out[m,n] = sum_k ctx[m,k] * wo[n,k] + bo[n]
// M=8192, N=1024, K=1024. Wave tile 64x64 (16 MFMA per 8 loads), block
// 256x64, double-buffered fragment prefetch. Grid 1-D 512: f = nblk*32+mblk
// -> all 16 n-blocks of an m-stripe share an XCD (A-stripe L2-resident).
__global__ __launch_bounds__(256, 2) void ogemm_kernel(const __bf16* __restrict__ ctx,
                                                       const __bf16* __restrict__ wo_bf,
                                                       const float* __restrict__ bo,
                                                       float* __restrict__ out) {
    const int w = threadIdx.x >> 6, lane = threadIdx.x & 63;
    const int l15 = lane & 15, quad = lane >> 4;
    const int f = blockIdx.x;
    const int mblk = f & 31, nblk = f >> 5;
    const int m_base = mblk * 256 + w * 64;
    const int n_base = nblk * 64;

    f32x4 acc[4][4];
#pragma unroll
    for (int sub = 0; sub < 4; ++sub)
#pragma unroll
        for (int nb = 0; nb < 4; ++nb) acc[sub][nb] = zero4();

    const __bf16* arow = ctx + (size_t)(m_base + l15) * E_ + quad * 8;
    const __bf16* brow = wo_bf + (size_t)(n_base + l15) * E_ + quad * 8;

    // preload k=0 fragment set
    bf16x8 a[4], bb[4];
#pragma unroll
    for (int sub = 0; sub < 4; ++sub) a[sub] = *(const bf16x8*)(arow + (size_t)sub * 16 * E_);
#pragma unroll
    for (int nb = 0; nb < 4; ++nb) bb[nb] = *(const bf16x8*)(brow + (size_t)nb * 16 * E_);

    for (int kk = 0; kk < E_; kk += 64) {
        // prefetch k = kk+32
        bf16x8 an[4], bbn[4];
#pragma unroll
        for (int sub = 0; sub < 4; ++sub)
            an[sub] = *(const bf16x8*)(arow + (size_t)sub * 16 * E_ + kk + 32);
#pragma unroll
        for (int nb = 0; nb < 4; ++nb)
            bbn[nb] = *(const bf16x8*)(brow + (size_t)nb * 16 * E_ + kk + 32);
#pragma unroll
        for (int nb = 0; nb < 4; ++nb)
#pragma unroll
            for (int sub = 0; sub < 4; ++sub)
                acc[sub][nb] = MFMA16(a[sub], bb[nb], acc[sub][nb]);
        // prefetch k = kk+64 (wrap on last; discarded)
        const int k2 = (kk + 64) & (E_ - 1);
#pragma unroll
        for (int sub = 0; sub < 4; ++sub)
            a[sub] = *(const bf16x8*)(arow + (size_t)sub * 16 * E_ + k2);
#pragma unroll
        for (int nb = 0; nb < 4; ++nb)
            bb[nb] = *(const bf16x8*)(brow + (size_t)nb * 16 * E_ + k2);
#pragma unroll
        for (int nb = 0; nb < 4; ++nb)
#pragma unroll
            for (int sub = 0; sub < 4; ++sub)
                acc[sub][nb] = MFMA16(an[sub], bbn[nb], acc[sub][nb]);
    }

#pragma unroll
    for (int sub = 0; sub < 4; ++sub) {
#pragma unroll
        for (int nb = 0; nb < 4; ++nb) {
            const int col = n_base + nb * 16 + l15;
            const float bias = bo[col];
#pragma unroll
            for (int r = 0; r < 4; ++r) {
                const int row = m_base + sub * 16 + quad * 4 + r;
                out[(size_t)row * E_ + col] = acc[sub][nb][r] + bias;
            }
        }
    }
}

// ---------------------------------------------------------------------------
extern "C" void kernel_launch(void* const* d_in, const int* in_sizes, int n_in,
                              void* d_out, int out_size, void* d_ws, size_t ws_size,
                              hipStream_t stream) {
    const float* query = (const float*)d_in[0];
    const float* key_value = (const float*)d_in[1];
    const float* wq = (const float*)d_in[2];
    const float* bq = (const float*)d_in[3];
    const float* wk = (const float*)d_in[4];
    const float* bk = (const float*)d_in[5];
    const float* wv = (const float*)d_in[6];
    const float* bv = (const float*)d_in[7];
    const float* wo = (const float*)d_in[8];
    const float* bo = (const float*)d_in[9];
    float* out = (float*)d_out;

    // workspace layout (needs 66 MB): qh | kh | vh_p | ctx | wo_bf
    char* ws = (char*)d_ws;
    __bf16* qh = (__bf16*)(ws);                         // 16 MB [B,H,SQ,D]
    __bf16* kh = (__bf16*)(ws + (16u << 20));           // 16 MB [B,H,SKV,D]
    __bf16* vh_p = (__bf16*)(ws + (32u << 20));         // 16 MB [B,H,D,SKV] (permuted)
    __bf16* ctxb = (__bf16*)(ws + (48u << 20));         // 16 MB [B,SQ,E]
    __bf16* wo_bf = (__bf16*)(ws + (64u << 20));        // 2 MB  [E,E]

    hipLaunchKernelGGL(cast_wo_kernel, dim3(E_ * E_ / 1024), dim3(256), 0, stream, wo, wo_bf);
    hipLaunchKernelGGL(proj_q_kernel, dim3(SQ_ / 64, H_, B_), dim3(256), 0, stream,
                       query, wq, bq, qh);
    hipLaunchKernelGGL(proj_kv_kernel, dim3(SKV_ / 64, H_, B_), dim3(256), 0, stream,
                       key_value, wk, bk, wv, bv, kh, vh_p);
    hipLaunchKernelGGL(attn_kernel, dim3(B_ * H_ * (SQ_ / 256)), dim3(256), 0, stream,
                       qh, kh, vh_p, ctxb);
    hipLaunchKernelGGL(ogemm_kernel, dim3((B_ * SQ_ / 256) * (E_ / 64)), dim3(256), 0, stream,
                       ctxb, wo_bf, bo, out);
}

// Round 6
// 329.232 us; speedup vs baseline: 2.1866x; 1.3859x over previous
//
#include <hip/hip_runtime.h>

#define B_ 4
#define SQ_ 2048
#define SKV_ 2048
#define E_ 1024
#define H_ 16
#define D_ 64

typedef __bf16 bf16x8 __attribute__((ext_vector_type(8)));
typedef __bf16 bf16x4 __attribute__((ext_vector_type(4)));
typedef float f32x4 __attribute__((ext_vector_type(4)));

__device__ inline f32x4 zero4() { f32x4 z = {0.f, 0.f, 0.f, 0.f}; return z; }

// Convert 8 consecutive f32 (32B-aligned) to a bf16x8 MFMA fragment.
__device__ inline bf16x8 cvt8(const float* __restrict__ p) {
    const float4 a = ((const float4*)p)[0];
    const float4 b = ((const float4*)p)[1];
    bf16x8 r;
    r[0] = (__bf16)a.x; r[1] = (__bf16)a.y; r[2] = (__bf16)a.z; r[3] = (__bf16)a.w;
    r[4] = (__bf16)b.x; r[5] = (__bf16)b.y; r[6] = (__bf16)b.z; r[7] = (__bf16)b.w;
    return r;
}

#define MFMA16(a, b, c) __builtin_amdgcn_mfma_f32_16x16x32_bf16(a, b, c, 0, 0, 0)

// exp(score/8) = 2^(score * 0.125 * log2(e)); folded into qh at projection.
#define QSCALE 0.18033688011112042f

// async global->LDS, 16B per lane; LDS dest is wave-uniform base + lane*16.
__device__ inline void stage16(const __bf16* g, __bf16* l) {
    __builtin_amdgcn_global_load_lds(
        (const __attribute__((address_space(1))) void*)g,
        (__attribute__((address_space(3))) void*)l, 16, 0, 0);
}

// ---------------------------------------------------------------------------
__global__ __launch_bounds__(256) void cast_wo_kernel(const float* __restrict__ wo,
                                                      __bf16* __restrict__ wo_bf) {
    int i = (blockIdx.x * 256 + threadIdx.x) * 4;
    float4 v = *(const float4*)(wo + i);
    wo_bf[i + 0] = (__bf16)v.x;
    wo_bf[i + 1] = (__bf16)v.y;
    wo_bf[i + 2] = (__bf16)v.z;
    wo_bf[i + 3] = (__bf16)v.w;
}

// ---------------------------------------------------------------------------
// Q projection (scaled by QSCALE for exp2-based softmax).
__global__ __launch_bounds__(256) void proj_q_kernel(const float* __restrict__ q,
                                                     const float* __restrict__ wq,
                                                     const float* __restrict__ bq,
                                                     __bf16* __restrict__ qh) {
    const int w = threadIdx.x >> 6, lane = threadIdx.x & 63;
    const int l15 = lane & 15, quad = lane >> 4;
    const int b = blockIdx.z, h = blockIdx.y;
    const int s_base = blockIdx.x * 64 + w * 16;

    const float* qrow = q + ((size_t)b * SQ_ + s_base + l15) * E_ + h * D_ + quad * 8;
    bf16x8 a0 = cvt8(qrow);
    bf16x8 a1 = cvt8(qrow + 32);

    f32x4 acc[4] = {zero4(), zero4(), zero4(), zero4()};
#pragma unroll
    for (int nb = 0; nb < 4; ++nb) {
        const float* wrow = wq + (size_t)h * D_ * D_ + (nb * 16 + l15) * D_ + quad * 8;
        bf16x8 b0 = cvt8(wrow);
        bf16x8 b1 = cvt8(wrow + 32);
        acc[nb] = MFMA16(a0, b0, acc[nb]);
        acc[nb] = MFMA16(a1, b1, acc[nb]);
    }

    __bf16* obase = qh + ((size_t)(b * H_ + h) * SQ_ + s_base) * D_;
#pragma unroll
    for (int nb = 0; nb < 4; ++nb) {
        const int col = nb * 16 + l15;
        const float bias = bq[h * D_ + col];
#pragma unroll
        for (int r = 0; r < 4; ++r) {
            obase[(quad * 4 + r) * D_ + col] = (__bf16)((acc[nb][r] + bias) * QSCALE);
        }
    }
}

// ---------------------------------------------------------------------------
// KV projection. New tile layouts for LDS staging in attention:
//   kh: [B,H, SKV] rows x 64 cols, 16B-chunk-swizzled within each 64-row tile:
//       element (t, d) stored at col chunk (d>>3) ^ (t&7).
//   vh: [B,H, SKV/64 tile, 64 d-rows, 64 pos], pos = permuted t
//       (pos = (tt&15)*4 + (tt>>4)) then chunk-swizzled by (d&7).
// Both are 8 KB contiguous per 64-kv tile -> global_load_lds friendly, and
// fragment ds_read_b128 hits the minimal 8-phase bank pattern.
__global__ __launch_bounds__(256) void proj_kv_kernel(const float* __restrict__ kv,
                                                      const float* __restrict__ wk,
                                                      const float* __restrict__ bk,
                                                      const float* __restrict__ wv,
                                                      const float* __restrict__ bv,
                                                      __bf16* __restrict__ kh,
                                                      __bf16* __restrict__ vh) {
    const int w = threadIdx.x >> 6, lane = threadIdx.x & 63;
    const int l15 = lane & 15, quad = lane >> 4;
    const int b = blockIdx.z, h = blockIdx.y;
    const int t_base = blockIdx.x * 64 + w * 16;

    const float* xrow = kv + ((size_t)b * SKV_ + t_base + l15) * E_ + h * D_ + quad * 8;
    bf16x8 a0 = cvt8(xrow);
    bf16x8 a1 = cvt8(xrow + 32);

    f32x4 acck[4] = {zero4(), zero4(), zero4(), zero4()};
    f32x4 accv[4] = {zero4(), zero4(), zero4(), zero4()};
#pragma unroll
    for (int nb = 0; nb < 4; ++nb) {
        const float* wkrow = wk + (size_t)h * D_ * D_ + (nb * 16 + l15) * D_ + quad * 8;
        const float* wvrow = wv + (size_t)h * D_ * D_ + (nb * 16 + l15) * D_ + quad * 8;
        bf16x8 bk0 = cvt8(wkrow);
        bf16x8 bk1 = cvt8(wkrow + 32);
        bf16x8 bv0 = cvt8(wvrow);
        bf16x8 bv1 = cvt8(wvrow + 32);
        acck[nb] = MFMA16(a0, bk0, acck[nb]);
        acck[nb] = MFMA16(a1, bk1, acck[nb]);
        accv[nb] = MFMA16(a0, bv0, accv[nb]);
        accv[nb] = MFMA16(a1, bv1, accv[nb]);
    }

    const int bh = b * H_ + h;
    __bf16* kbase = kh + ((size_t)bh * SKV_ + t_base) * D_;
    __bf16* vbase = vh + (((size_t)bh * (SKV_ / 64) + blockIdx.x) * 64) * 64;
#pragma unroll
    for (int nb = 0; nb < 4; ++nb) {
        const int col = nb * 16 + l15;  // K: head-dim d. V: head-dim d (row).
        const float biask = bk[h * D_ + col];
        const float biasv = bv[h * D_ + col];
#pragma unroll
        for (int r = 0; r < 4; ++r) {
            const int row = quad * 4 + r;  // t within this wave's 16-row slab
            // K: tile row rit = w*16+row; rit&7 = row&7. Swizzle col chunk.
            const int kcol = (((col >> 3) ^ (row & 7)) << 3) | (col & 7);
            kbase[row * D_ + kcol] = (__bf16)(acck[nb][r] + biask);
            // V: tt = w*16+row; pos = (tt&15)*4 + (tt>>4) = row*4 + w,
            // then chunk-swizzle by d&7 = col&7.
            const int p = row * 4 + w;
            const int vcol = (((p >> 3) ^ (col & 7)) << 3) | (p & 7);
            vbase[(size_t)col * 64 + vcol] = (__bf16)(accv[nb][r] + biasv);
        }
    }
}

// ---------------------------------------------------------------------------
// Attention v4: LDS-staged flash attention. Block = 128 q-rows (4 waves x
// 32 rows = 2 q-tiles each). K/V 64x64 tiles staged per BLOCK via
// global_load_lds (swizzled layouts, contiguous 8 KB), double-buffered:
// stage(t+1) issues at tile top, one __syncthreads per tile, prefetch covered
// by the whole compute phase. No max subtraction (scores unit-variance);
// row-sum partials reduced by epilogue shuffles. LDS 50.4 KB -> 3 blocks/CU.
// Grid 1-D 1024: f = tq*64 + g, g=b*16+h -> all tiles of one (b,h) on one XCD.
__global__ __launch_bounds__(256, 3) void attn_kernel(const __bf16* __restrict__ qh,
                                                      const __bf16* __restrict__ kh,
                                                      const __bf16* __restrict__ vh,
                                                      __bf16* __restrict__ ctx) {
    __shared__ __bf16 k_lds[2][4096];          // 64 t-rows x 64 d (swizzled)
    __shared__ __bf16 v_lds[2][4096];          // 64 d-rows x 64 pos (swizzled)
    __shared__ __bf16 p_lds[4][2][16][72];     // per-wave P round-trip

    const int w = threadIdx.x >> 6, lane = threadIdx.x & 63;
    const int l15 = lane & 15, quad = lane >> 4;
    const int f = blockIdx.x;
    const int g = f & 63, tq = f >> 6;
    const int b = g >> 4, h = g & 15;
    const int bh = b * H_ + h;
    const int s_base = tq * 128 + w * 32;
    const int sw8 = (l15 & 7) << 3;  // fragment-read swizzle (row&7 == l15&7)

    bf16x8 aq[2][2];
#pragma unroll
    for (int qt = 0; qt < 2; ++qt) {
        const __bf16* qb = qh + ((size_t)bh * SQ_ + s_base + qt * 16 + l15) * D_ + quad * 8;
        aq[qt][0] = *(const bf16x8*)qb;
        aq[qt][1] = *(const bf16x8*)(qb + 32);
    }

    f32x4 o[2][4];
    float l_r[2][4];
#pragma unroll
    for (int qt = 0; qt < 2; ++qt) {
#pragma unroll
        for (int nb = 0; nb < 4; ++nb) o[qt][nb] = zero4();
#pragma unroll
        for (int r = 0; r < 4; ++r) l_r[qt][r] = 0.f;
    }

    const __bf16* kt = kh + (size_t)bh * SKV_ * D_;  // tile it at +it*4096
    const __bf16* vt = vh + (size_t)bh * SKV_ * D_;  // same stride (tiled)

    // stage one 64-kv tile (K 8KB + V 8KB); each wave: 2+2 calls of 1KB.
    auto stage = [&](int buf, int it) {
#pragma unroll
        for (int c2 = 0; c2 < 2; ++c2) {
            const int c = w + c2 * 4;
            stage16(kt + (size_t)it * 4096 + c * 512 + lane * 8, &k_lds[buf][c * 512]);
            stage16(vt + (size_t)it * 4096 + c * 512 + lane * 8, &v_lds[buf][c * 512]);
        }
    };

    stage(0, 0);
    __syncthreads();

    for (int it = 0; it < SKV_ / 64; ++it) {
        const int cur = it & 1;
        if (it + 1 < SKV_ / 64) stage(cur ^ 1, it + 1);  // async into other buf

        // K fragments from LDS (shared by both q-tiles)
        bf16x8 kf0[4], kf1[4];
#pragma unroll
        for (int nb = 0; nb < 4; ++nb) {
            const __bf16* kr = &k_lds[cur][(nb * 16 + l15) * 64];
            kf0[nb] = *(const bf16x8*)&kr[(quad << 3) ^ sw8];
            kf1[nb] = *(const bf16x8*)&kr[((quad + 4) << 3) ^ sw8];
        }
        // QK^T + exp per q-tile
#pragma unroll
        for (int qt = 0; qt < 2; ++qt) {
            f32x4 s[4] = {zero4(), zero4(), zero4(), zero4()};
#pragma unroll
            for (int nb = 0; nb < 4; ++nb) {
                s[nb] = MFMA16(aq[qt][0], kf0[nb], s[nb]);
                s[nb] = MFMA16(aq[qt][1], kf1[nb], s[nb]);
            }
#pragma unroll
            for (int r = 0; r < 4; ++r) {
                const float p0 = __builtin_amdgcn_exp2f(s[0][r]);
                const float p1 = __builtin_amdgcn_exp2f(s[1][r]);
                const float p2 = __builtin_amdgcn_exp2f(s[2][r]);
                const float p3 = __builtin_amdgcn_exp2f(s[3][r]);
                l_r[qt][r] += (p0 + p1) + (p2 + p3);
                bf16x4 p;
                p[0] = (__bf16)p0; p[1] = (__bf16)p1;
                p[2] = (__bf16)p2; p[3] = (__bf16)p3;
                *(bf16x4*)&p_lds[w][qt][quad * 4 + r][l15 * 4] = p;
            }
        }
        // V fragments from LDS
        bf16x8 vf0[4], vf1[4];
#pragma unroll
        for (int nb = 0; nb < 4; ++nb) {
            const __bf16* vr = &v_lds[cur][(nb * 16 + l15) * 64];
            vf0[nb] = *(const bf16x8*)&vr[(quad << 3) ^ sw8];
            vf1[nb] = *(const bf16x8*)&vr[((quad + 4) << 3) ^ sw8];
        }
        // O += P V
#pragma unroll
        for (int qt = 0; qt < 2; ++qt) {
#pragma unroll
            for (int ks = 0; ks < 2; ++ks) {
                bf16x8 ap = *(const bf16x8*)&p_lds[w][qt][l15][ks * 32 + quad * 8];
#pragma unroll
                for (int nb = 0; nb < 4; ++nb)
                    o[qt][nb] = MFMA16(ap, (ks == 0) ? vf0[nb] : vf1[nb], o[qt][nb]);
            }
        }
        __syncthreads();  // readers of cur done; next-stage loads drained
    }

    __bf16* cbase = ctx + ((size_t)b * SQ_ + s_base) * E_ + h * D_;
#pragma unroll
    for (int qt = 0; qt < 2; ++qt) {
#pragma unroll
        for (int r = 0; r < 4; ++r) {
            float l = l_r[qt][r];
            l += __shfl_xor(l, 1);
            l += __shfl_xor(l, 2);
            l += __shfl_xor(l, 4);
            l += __shfl_xor(l, 8);
            const float inv = 1.f / l;
            const int row = qt * 16 + quad * 4 + r;
#pragma unroll
            for (int nb = 0; nb < 4; ++nb) {
                cbase[row * E_ + nb * 16 + l15] = (__bf16)(o[qt][nb][r] * inv);
            }
        }
    }
}

// ---------------------------------------------------------------------------
// Output GEMM: out[m,n] = sum_k ctx[m,k] * wo[n,k] + bo[n]
// M=8192, N=1024, K=1024. Wave tile 64x64 (16 MFMA per 8 loads), block
// 256x64, double-buffered fragment prefetch. Grid 1-D 512: f = nblk*32+mblk
// -> all 16 n-blocks of an m-stripe share an XCD (A-stripe L2-resident).
__global__ __launch_bounds__(256, 2) void ogemm_kernel(const __bf16* __restrict__ ctx,
                                                       const __bf16* __restrict__ wo_bf,
                                                       const float* __restrict__ bo,
                                                       float* __restrict__ out) {
    const int w = threadIdx.x >> 6, lane = threadIdx.x & 63;
    const int l15 = lane & 15, quad = lane >> 4;
    const int f = blockIdx.x;
    const int mblk = f & 31, nblk = f >> 5;
    const int m_base = mblk * 256 + w * 64;
    const int n_base = nblk * 64;

    f32x4 acc[4][4];
#pragma unroll
    for (int sub = 0; sub < 4; ++sub)
#pragma unroll
        for (int nb = 0; nb < 4; ++nb) acc[sub][nb] = zero4();

    const __bf16* arow = ctx + (size_t)(m_base + l15) * E_ + quad * 8;
    const __bf16* brow = wo_bf + (size_t)(n_base + l15) * E_ + quad * 8;

    // preload k=0 fragment set
    bf16x8 a[4], bb[4];
#pragma unroll
    for (int sub = 0; sub < 4; ++sub) a[sub] = *(const bf16x8*)(arow + (size_t)sub * 16 * E_);
#pragma unroll
    for (int nb = 0; nb < 4; ++nb) bb[nb] = *(const bf16x8*)(brow + (size_t)nb * 16 * E_);

    for (int kk = 0; kk < E_; kk += 64) {
        // prefetch k = kk+32
        bf16x8 an[4], bbn[4];
#pragma unroll
        for (int sub = 0; sub < 4; ++sub)
            an[sub] = *(const bf16x8*)(arow + (size_t)sub * 16 * E_ + kk + 32);
#pragma unroll
        for (int nb = 0; nb < 4; ++nb)
            bbn[nb] = *(const bf16x8*)(brow + (size_t)nb * 16 * E_ + kk + 32);
#pragma unroll
        for (int nb = 0; nb < 4; ++nb)
#pragma unroll
            for (int sub = 0; sub < 4; ++sub)
                acc[sub][nb] = MFMA16(a[sub], bb[nb], acc[sub][nb]);
        // prefetch k = kk+64 (wrap on last; discarded)
        const int k2 = (kk + 64) & (E_ - 1);
#pragma unroll
        for (int sub = 0; sub < 4; ++sub)
            a[sub] = *(const bf16x8*)(arow + (size_t)sub * 16 * E_ + k2);
#pragma unroll
        for (int nb = 0; nb < 4; ++nb)
            bb[nb] = *(const bf16x8*)(brow + (size_t)nb * 16 * E_ + k2);
#pragma unroll
        for (int nb = 0; nb < 4; ++nb)
#pragma unroll
            for (int sub = 0; sub < 4; ++sub)
                acc[sub][nb] = MFMA16(an[sub], bbn[nb], acc[sub][nb]);
    }

#pragma unroll
    for (int sub = 0; sub < 4; ++sub) {
#pragma unroll
        for (int nb = 0; nb < 4; ++nb) {
            const int col = n_base + nb * 16 + l15;
            const float bias = bo[col];
#pragma unroll
            for (int r = 0; r < 4; ++r) {
                const int row = m_base + sub * 16 + quad * 4 + r;
                out[(size_t)row * E_ + col] = acc[sub][nb][r] + bias;
            }
        }
    }
}

// ---------------------------------------------------------------------------
extern "C" void kernel_launch(void* const* d_in, const int* in_sizes, int n_in,
                              void* d_out, int out_size, void* d_ws, size_t ws_size,
                              hipStream_t stream) {
    const float* query = (const float*)d_in[0];
    const float* key_value = (const float*)d_in[1];
    const float* wq = (const float*)d_in[2];
    const float* bq = (const float*)d_in[3];
    const float* wk = (const float*)d_in[4];
    const float* bk = (const float*)d_in[5];
    const float* wv = (const float*)d_in[6];
    const float* bv = (const float*)d_in[7];
    const float* wo = (const float*)d_in[8];
    const float* bo = (const float*)d_in[9];
    float* out = (float*)d_out;

    // workspace layout (needs 66 MB): qh | kh | vh | ctx | wo_bf
    char* ws = (char*)d_ws;
    __bf16* qh = (__bf16*)(ws);                         // 16 MB [B,H,SQ,D]
    __bf16* kh = (__bf16*)(ws + (16u << 20));           // 16 MB [B,H,SKV,D] swizzled tiles
    __bf16* vh = (__bf16*)(ws + (32u << 20));           // 16 MB [B,H,SKV/64,D,64] perm+swizzled
    __bf16* ctxb = (__bf16*)(ws + (48u << 20));         // 16 MB [B,SQ,E]
    __bf16* wo_bf = (__bf16*)(ws + (64u << 20));        // 2 MB  [E,E]

    hipLaunchKernelGGL(cast_wo_kernel, dim3(E_ * E_ / 1024), dim3(256), 0, stream, wo, wo_bf);
    hipLaunchKernelGGL(proj_q_kernel, dim3(SQ_ / 64, H_, B_), dim3(256), 0, stream,
                       query, wq, bq, qh);
    hipLaunchKernelGGL(proj_kv_kernel, dim3(SKV_ / 64, H_, B_), dim3(256), 0, stream,
                       key_value, wk, bk, wv, bv, kh, vh);
    hipLaunchKernelGGL(attn_kernel, dim3(B_ * H_ * (SQ_ / 128)), dim3(256), 0, stream,
                       qh, kh, vh, ctxb);
    hipLaunchKernelGGL(ogemm_kernel, dim3((B_ * SQ_ / 256) * (E_ / 64)), dim3(256), 0, stream,
                       ctxb, wo_bf, bo, out);
}

// Round 8
// 316.033 us; speedup vs baseline: 2.2779x; 1.0418x over previous
//
#include <hip/hip_runtime.h>

#define B_ 4
#define SQ_ 2048
#define SKV_ 2048
#define E_ 1024
#define H_ 16
#define D_ 64

typedef __bf16 bf16x8 __attribute__((ext_vector_type(8)));
typedef __bf16 bf16x4 __attribute__((ext_vector_type(4)));
typedef float f32x4 __attribute__((ext_vector_type(4)));
typedef short short4v __attribute__((ext_vector_type(4)));

__device__ inline f32x4 zero4() { f32x4 z = {0.f, 0.f, 0.f, 0.f}; return z; }

// Convert 8 consecutive f32 (32B-aligned) to a bf16x8 MFMA fragment.
__device__ inline bf16x8 cvt8(const float* __restrict__ p) {
    const float4 a = ((const float4*)p)[0];
    const float4 b = ((const float4*)p)[1];
    bf16x8 r;
    r[0] = (__bf16)a.x; r[1] = (__bf16)a.y; r[2] = (__bf16)a.z; r[3] = (__bf16)a.w;
    r[4] = (__bf16)b.x; r[5] = (__bf16)b.y; r[6] = (__bf16)b.z; r[7] = (__bf16)b.w;
    return r;
}

#define MFMA16(a, b, c) __builtin_amdgcn_mfma_f32_16x16x32_bf16(a, b, c, 0, 0, 0)

// K=16 bf16 MFMA for the register-direct PV (A/B frag: k = quad*4 + j).
// Builtin selection must only happen on the DEVICE pass (host pass sees no
// amdgcn builtins — R7's #error fired there).
__device__ inline f32x4 pv_mfma(bf16x4 a, bf16x4 b, f32x4 c) {
#if defined(__HIP_DEVICE_COMPILE__)
#if __has_builtin(__builtin_amdgcn_mfma_f32_16x16x16_bf16)
    return __builtin_amdgcn_mfma_f32_16x16x16_bf16(a, b, c, 0, 0, 0);
#else
    return __builtin_amdgcn_mfma_f32_16x16x16bf16_1k(
        __builtin_bit_cast(short4v, a), __builtin_bit_cast(short4v, b), c, 0, 0, 0);
#endif
#else
    (void)a; (void)b;
    return c;  // host stub, never executed
#endif
}

// exp(score/8) = 2^(score * 0.125 * log2(e)); folded into qh at projection.
#define QSCALE 0.18033688011112042f

// async global->LDS, 16B per lane; LDS dest is wave-uniform base + lane*16.
__device__ inline void stage16(const __bf16* g, __bf16* l) {
    __builtin_amdgcn_global_load_lds(
        (const __attribute__((address_space(1))) void*)g,
        (__attribute__((address_space(3))) void*)l, 16, 0, 0);
}

// ---------------------------------------------------------------------------
__global__ __launch_bounds__(256) void cast_wo_kernel(const float* __restrict__ wo,
                                                      __bf16* __restrict__ wo_bf) {
    int i = (blockIdx.x * 256 + threadIdx.x) * 4;
    float4 v = *(const float4*)(wo + i);
    wo_bf[i + 0] = (__bf16)v.x;
    wo_bf[i + 1] = (__bf16)v.y;
    wo_bf[i + 2] = (__bf16)v.z;
    wo_bf[i + 3] = (__bf16)v.w;
}

// ---------------------------------------------------------------------------
// Q projection (scaled by QSCALE for exp2-based softmax).
__global__ __launch_bounds__(256) void proj_q_kernel(const float* __restrict__ q,
                                                     const float* __restrict__ wq,
                                                     const float* __restrict__ bq,
                                                     __bf16* __restrict__ qh) {
    const int w = threadIdx.x >> 6, lane = threadIdx.x & 63;
    const int l15 = lane & 15, quad = lane >> 4;
    const int b = blockIdx.z, h = blockIdx.y;
    const int s_base = blockIdx.x * 64 + w * 16;

    const float* qrow = q + ((size_t)b * SQ_ + s_base + l15) * E_ + h * D_ + quad * 8;
    bf16x8 a0 = cvt8(qrow);
    bf16x8 a1 = cvt8(qrow + 32);

    f32x4 acc[4] = {zero4(), zero4(), zero4(), zero4()};
#pragma unroll
    for (int nb = 0; nb < 4; ++nb) {
        const float* wrow = wq + (size_t)h * D_ * D_ + (nb * 16 + l15) * D_ + quad * 8;
        bf16x8 b0 = cvt8(wrow);
        bf16x8 b1 = cvt8(wrow + 32);
        acc[nb] = MFMA16(a0, b0, acc[nb]);
        acc[nb] = MFMA16(a1, b1, acc[nb]);
    }

    __bf16* obase = qh + ((size_t)(b * H_ + h) * SQ_ + s_base) * D_;
#pragma unroll
    for (int nb = 0; nb < 4; ++nb) {
        const int col = nb * 16 + l15;
        const float bias = bq[h * D_ + col];
#pragma unroll
        for (int r = 0; r < 4; ++r) {
            obase[(quad * 4 + r) * D_ + col] = (__bf16)((acc[nb][r] + bias) * QSCALE);
        }
    }
}

// ---------------------------------------------------------------------------
// KV projection. Tile layouts for LDS staging in attention:
//   kh: per 64-row tile, element (t,d) at col chunk (d>>3)^(t&7)  [rows t].
//   vh: V TRANSPOSED per tile: [d=64 rows][t=64 cols], element (d,t) at
//       col chunk (t>>3)^(d&7). Both 8 KB contiguous per 64-kv tile.
__global__ __launch_bounds__(256) void proj_kv_kernel(const float* __restrict__ kv,
                                                      const float* __restrict__ wk,
                                                      const float* __restrict__ bk,
                                                      const float* __restrict__ wv,
                                                      const float* __restrict__ bv,
                                                      __bf16* __restrict__ kh,
                                                      __bf16* __restrict__ vh) {
    const int w = threadIdx.x >> 6, lane = threadIdx.x & 63;
    const int l15 = lane & 15, quad = lane >> 4;
    const int b = blockIdx.z, h = blockIdx.y;
    const int t_base = blockIdx.x * 64 + w * 16;

    const float* xrow = kv + ((size_t)b * SKV_ + t_base + l15) * E_ + h * D_ + quad * 8;
    bf16x8 a0 = cvt8(xrow);
    bf16x8 a1 = cvt8(xrow + 32);

    f32x4 acck[4] = {zero4(), zero4(), zero4(), zero4()};
    f32x4 accv[4] = {zero4(), zero4(), zero4(), zero4()};
#pragma unroll
    for (int nb = 0; nb < 4; ++nb) {
        const float* wkrow = wk + (size_t)h * D_ * D_ + (nb * 16 + l15) * D_ + quad * 8;
        const float* wvrow = wv + (size_t)h * D_ * D_ + (nb * 16 + l15) * D_ + quad * 8;
        bf16x8 bk0 = cvt8(wkrow);
        bf16x8 bk1 = cvt8(wkrow + 32);
        bf16x8 bv0 = cvt8(wvrow);
        bf16x8 bv1 = cvt8(wvrow + 32);
        acck[nb] = MFMA16(a0, bk0, acck[nb]);
        acck[nb] = MFMA16(a1, bk1, acck[nb]);
        accv[nb] = MFMA16(a0, bv0, accv[nb]);
        accv[nb] = MFMA16(a1, bv1, accv[nb]);
    }

    const int bh = b * H_ + h;
    __bf16* kbase = kh + ((size_t)bh * SKV_ + t_base) * D_;
    __bf16* vbase = vh + (((size_t)bh * (SKV_ / 64) + blockIdx.x) * 64) * 64;
#pragma unroll
    for (int nb = 0; nb < 4; ++nb) {
        const int col = nb * 16 + l15;  // head-dim d
        const float biask = bk[h * D_ + col];
        const float biasv = bv[h * D_ + col];
#pragma unroll
        for (int r = 0; r < 4; ++r) {
            const int row = quad * 4 + r;        // t within wave's 16-row slab
            // K: tile row's &7 == row&7; swizzle col chunk by it.
            const int kcol = (((col >> 3) ^ (row & 7)) << 3) | (col & 7);
            kbase[row * D_ + kcol] = (__bf16)(acck[nb][r] + biask);
            // V^T: row d=col, col t=tl; chunk swizzled by d&7.
            const int tl = w * 16 + row;         // tile-local t
            const int vcol = (((tl >> 3) ^ (col & 7)) << 3) | (tl & 7);
            vbase[(size_t)col * 64 + vcol] = (__bf16)(accv[nb][r] + biasv);
        }
    }
}

// ---------------------------------------------------------------------------
// Attention v5: transpose-free flash attention.
//   S^T = K·Q^T via MFMA(A=K-frag, B=Q-frag): C-layout col = q = lane&15.
//   P^T = exp2(S^T) feeds PV DIRECTLY from registers: the C-layout rows
//   (t = quad*4+r per 16-block) match the 16x16x16 A/B k-layout (k=quad*4+j).
//   O^T[d][q] += V^T-frag(A) · P^T-frag(B), 16x16x16 bf16 MFMA. No P LDS.
// Block = 256 q-rows (4 waves x 64 rows = 4 q-tiles each). K/V 64x64 tiles
// staged per block via global_load_lds, double-buffered, 1 barrier/tile.
// Row sums: per-lane partials (lane=q), 2 shuffles at epilogue; O^T
// transposed per wave through a small LDS buffer for coalesced stores.
// Grid 1-D 512: f = tq*64 + g, g=b*16+h -> all tiles of one (b,h) on one XCD.
__global__ __launch_bounds__(256, 2) void attn_kernel(const __bf16* __restrict__ qh,
                                                      const __bf16* __restrict__ kh,
                                                      const __bf16* __restrict__ vh,
                                                      __bf16* __restrict__ ctx) {
    __shared__ __bf16 k_lds[2][4096];       // 64 t-rows x 64 d (swizzled)
    __shared__ __bf16 v_lds[2][4096];       // 64 d-rows x 64 t (swizzled)
    __shared__ __bf16 t_lds[4][16][72];     // per-wave epilogue transpose

    const int w = threadIdx.x >> 6, lane = threadIdx.x & 63;
    const int l15 = lane & 15, quad = lane >> 4;
    const int f = blockIdx.x;
    const int g = f & 63, tq = f >> 6;
    const int b = g >> 4, h = g & 15;
    const int bh = b * H_ + h;
    const int s_base = tq * 256 + w * 64;
    const int sw8 = (l15 & 7) << 3;

    bf16x8 aq[4][2];
#pragma unroll
    for (int qt = 0; qt < 4; ++qt) {
        const __bf16* qb = qh + ((size_t)bh * SQ_ + s_base + qt * 16 + l15) * D_ + quad * 8;
        aq[qt][0] = *(const bf16x8*)qb;
        aq[qt][1] = *(const bf16x8*)(qb + 32);
    }

    f32x4 oT[4][4];   // [qt][d-block], C-layout: col=q=lane&15, row=d=quad*4+r
    float l_part[4];
#pragma unroll
    for (int qt = 0; qt < 4; ++qt) {
        l_part[qt] = 0.f;
#pragma unroll
        for (int db = 0; db < 4; ++db) oT[qt][db] = zero4();
    }

    const __bf16* kt = kh + (size_t)bh * SKV_ * D_;
    const __bf16* vt = vh + (size_t)bh * SKV_ * D_;

    auto stage = [&](int buf, int it) {
#pragma unroll
        for (int c2 = 0; c2 < 2; ++c2) {
            const int c = w + c2 * 4;
            stage16(kt + (size_t)it * 4096 + c * 512 + lane * 8, &k_lds[buf][c * 512]);
            stage16(vt + (size_t)it * 4096 + c * 512 + lane * 8, &v_lds[buf][c * 512]);
        }
    };

    stage(0, 0);
    __syncthreads();

    for (int it = 0; it < SKV_ / 64; ++it) {
        const int cur = it & 1;
        if (it + 1 < SKV_ / 64) stage(cur ^ 1, it + 1);

        // K fragments (A-operand of S^T): lane = t, k = d = quad*8+j
        bf16x8 kf0[4], kf1[4];
#pragma unroll
        for (int nb = 0; nb < 4; ++nb) {
            const __bf16* kr = &k_lds[cur][(nb * 16 + l15) * 64];
            kf0[nb] = *(const bf16x8*)&kr[(quad << 3) ^ sw8];
            kf1[nb] = *(const bf16x8*)&kr[((quad + 4) << 3) ^ sw8];
        }
        // V^T fragments (A-operand of PV): lane = d, k = t = quad*4+j
        bf16x4 vtf[4][4];
#pragma unroll
        for (int db = 0; db < 4; ++db) {
            const __bf16* vr = &v_lds[cur][(db * 16 + l15) * 64];
#pragma unroll
            for (int nb = 0; nb < 4; ++nb) {
                const int c = nb * 2 + (quad >> 1);
                const int off = (((c ^ (l15 & 7)) << 3) | ((quad & 1) * 4));
                vtf[db][nb] = *(const bf16x4*)&vr[off];
            }
        }
        // per q-tile: S^T -> exp -> PV (register-direct)
#pragma unroll
        for (int qt = 0; qt < 4; ++qt) {
            f32x4 s[4] = {zero4(), zero4(), zero4(), zero4()};
#pragma unroll
            for (int nb = 0; nb < 4; ++nb) {
                s[nb] = MFMA16(kf0[nb], aq[qt][0], s[nb]);
                s[nb] = MFMA16(kf1[nb], aq[qt][1], s[nb]);
            }
            bf16x4 p4[4];
            float lsum = 0.f;
#pragma unroll
            for (int nb = 0; nb < 4; ++nb) {
                const float e0 = __builtin_amdgcn_exp2f(s[nb][0]);
                const float e1 = __builtin_amdgcn_exp2f(s[nb][1]);
                const float e2 = __builtin_amdgcn_exp2f(s[nb][2]);
                const float e3 = __builtin_amdgcn_exp2f(s[nb][3]);
                lsum += (e0 + e1) + (e2 + e3);
                bf16x4 p;
                p[0] = (__bf16)e0; p[1] = (__bf16)e1;
                p[2] = (__bf16)e2; p[3] = (__bf16)e3;
                p4[nb] = p;
            }
            l_part[qt] += lsum;
#pragma unroll
            for (int db = 0; db < 4; ++db)
#pragma unroll
                for (int nb = 0; nb < 4; ++nb)
                    oT[qt][db] = pv_mfma(vtf[db][nb], p4[nb], oT[qt][db]);
        }
        __syncthreads();
    }

    // epilogue: row sums (lane=q already), scale, transpose via LDS, store
#pragma unroll
    for (int qt = 0; qt < 4; ++qt) {
        float l = l_part[qt];
        l += __shfl_xor(l, 16);
        l += __shfl_xor(l, 32);
        const float inv = 1.f / l;
#pragma unroll
        for (int db = 0; db < 4; ++db) {
#pragma unroll
            for (int r = 0; r < 4; ++r) {
                t_lds[w][l15][db * 16 + quad * 4 + r] = (__bf16)(oT[qt][db][r] * inv);
            }
        }
        // same-wave read-back (no barrier): 8 lanes per q-row, 16B stores
#pragma unroll
        for (int pp = 0; pp < 2; ++pp) {
            const int row = (lane >> 3) + pp * 8;
            bf16x8 vrow = *(const bf16x8*)&t_lds[w][row][(lane & 7) * 8];
            *(bf16x8*)&ctx[((size_t)b * SQ_ + s_base + qt * 16 + row) * E_ + h * D_ +
                           (lane & 7) * 8] = vrow;
        }
    }
}

// ---------------------------------------------------------------------------
// Output GEMM: out[m,n] = sum_k ctx[m,k] * wo[n,k] + bo[n]
// M=8192, N=1024, K=1024. Wave tile 64x64, block 256x64, double-buffered
// fragment prefetch. Grid 1-D 512: f = nblk*32+mblk -> XCD-local A-stripe.
__global__ __launch_bounds__(256, 2) void ogemm_kernel(const __bf16* __restrict__ ctx,
                                                       const __bf16* __restrict__ wo_bf,
                                                       const float* __restrict__ bo,
                                                       float* __restrict__ out) {
    const int w = threadIdx.x >> 6, lane = threadIdx.x & 63;
    const int l15 = lane & 15, quad = lane >> 4;
    const int f = blockIdx.x;
    const int mblk = f & 31, nblk = f >> 5;
    const int m_base = mblk * 256 + w * 64;
    const int n_base = nblk * 64;

    f32x4 acc[4][4];
#pragma unroll
    for (int sub = 0; sub < 4; ++sub)
#pragma unroll
        for (int nb = 0; nb < 4; ++nb) acc[sub][nb] = zero4();

    const __bf16* arow = ctx + (size_t)(m_base + l15) * E_ + quad * 8;
    const __bf16* brow = wo_bf + (size_t)(n_base + l15) * E_ + quad * 8;

    bf16x8 a[4], bb[4];
#pragma unroll
    for (int sub = 0; sub < 4; ++sub) a[sub] = *(const bf16x8*)(arow + (size_t)sub * 16 * E_);
#pragma unroll
    for (int nb = 0; nb < 4; ++nb) bb[nb] = *(const bf16x8*)(brow + (size_t)nb * 16 * E_);

    for (int kk = 0; kk < E_; kk += 64) {
        bf16x8 an[4], bbn[4];
#pragma unroll
        for (int sub = 0; sub < 4; ++sub)
            an[sub] = *(const bf16x8*)(arow + (size_t)sub * 16 * E_ + kk + 32);
#pragma unroll
        for (int nb = 0; nb < 4; ++nb)
            bbn[nb] = *(const bf16x8*)(brow + (size_t)nb * 16 * E_ + kk + 32);
#pragma unroll
        for (int nb = 0; nb < 4; ++nb)
#pragma unroll
            for (int sub = 0; sub < 4; ++sub)
                acc[sub][nb] = MFMA16(a[sub], bb[nb], acc[sub][nb]);
        const int k2 = (kk + 64) & (E_ - 1);
#pragma unroll
        for (int sub = 0; sub < 4; ++sub)
            a[sub] = *(const bf16x8*)(arow + (size_t)sub * 16 * E_ + k2);
#pragma unroll
        for (int nb = 0; nb < 4; ++nb)
            bb[nb] = *(const bf16x8*)(brow + (size_t)nb * 16 * E_ + k2);
#pragma unroll
        for (int nb = 0; nb < 4; ++nb)
#pragma unroll
            for (int sub = 0; sub < 4; ++sub)
                acc[sub][nb] = MFMA16(an[sub], bbn[nb], acc[sub][nb]);
    }

#pragma unroll
    for (int sub = 0; sub < 4; ++sub) {
#pragma unroll
        for (int nb = 0; nb < 4; ++nb) {
            const int col = n_base + nb * 16 + l15;
            const float bias = bo[col];
#pragma unroll
            for (int r = 0; r < 4; ++r) {
                const int row = m_base + sub * 16 + quad * 4 + r;
                out[(size_t)row * E_ + col] = acc[sub][nb][r] + bias;
            }
        }
    }
}

// ---------------------------------------------------------------------------
extern "C" void kernel_launch(void* const* d_in, const int* in_sizes, int n_in,
                              void* d_out, int out_size, void* d_ws, size_t ws_size,
                              hipStream_t stream) {
    const float* query = (const float*)d_in[0];
    const float* key_value = (const float*)d_in[1];
    const float* wq = (const float*)d_in[2];
    const float* bq = (const float*)d_in[3];
    const float* wk = (const float*)d_in[4];
    const float* bk = (const float*)d_in[5];
    const float* wv = (const float*)d_in[6];
    const float* bv = (const float*)d_in[7];
    const float* wo = (const float*)d_in[8];
    const float* bo = (const float*)d_in[9];
    float* out = (float*)d_out;

    // workspace layout (needs 66 MB): qh | kh | vh | ctx | wo_bf
    char* ws = (char*)d_ws;
    __bf16* qh = (__bf16*)(ws);                         // 16 MB [B,H,SQ,D]
    __bf16* kh = (__bf16*)(ws + (16u << 20));           // 16 MB swizzled K tiles
    __bf16* vh = (__bf16*)(ws + (32u << 20));           // 16 MB swizzled V^T tiles
    __bf16* ctxb = (__bf16*)(ws + (48u << 20));         // 16 MB [B,SQ,E]
    __bf16* wo_bf = (__bf16*)(ws + (64u << 20));        // 2 MB  [E,E]

    hipLaunchKernelGGL(cast_wo_kernel, dim3(E_ * E_ / 1024), dim3(256), 0, stream, wo, wo_bf);
    hipLaunchKernelGGL(proj_q_kernel, dim3(SQ_ / 64, H_, B_), dim3(256), 0, stream,
                       query, wq, bq, qh);
    hipLaunchKernelGGL(proj_kv_kernel, dim3(SKV_ / 64, H_, B_), dim3(256), 0, stream,
                       key_value, wk, bk, wv, bv, kh, vh);
    hipLaunchKernelGGL(attn_kernel, dim3(B_ * H_ * (SQ_ / 256)), dim3(256), 0, stream,
                       qh, kh, vh, ctxb);
    hipLaunchKernelGGL(ogemm_kernel, dim3((B_ * SQ_ / 256) * (E_ / 64)), dim3(256), 0, stream,
                       ctxb, wo_bf, bo, out);
}